// Round 1
// baseline (352.648 us; speedup 1.0000x reference)
//
#include <hip/hip_runtime.h>
#include <stdint.h>

typedef unsigned short u16;
typedef __bf16 bfx8 __attribute__((ext_vector_type(8)));
typedef float f32x4 __attribute__((ext_vector_type(4)));

#define HD 768
#define NTREE 40000
#define NCODES 10000
#define GNN 1536
#define OUTD 512
#define NBV 512
#define VNEG (-1e30f)
#define TB 4

__device__ __forceinline__ float bf2f(u16 u) {
  union { uint32_t i; float f; } v; v.i = ((uint32_t)u) << 16; return v.f;
}
__device__ __forceinline__ u16 f2bf(float f) {
  union { float fl; uint32_t i; } v; v.fl = f;
  uint32_t u = v.i;
  u += 0x7FFFu + ((u >> 16) & 1u);
  return (u16)(u >> 16);
}

// ---------------- K0a: fp32 -> bf16 convert of embed table ----------------
__global__ void k_convE(const float* __restrict__ E, u16* __restrict__ Ebf, int n4) {
  int i = blockIdx.x * blockDim.x + threadIdx.x;
  if (i >= n4) return;
  float4 v = ((const float4*)E)[i];
  ushort4 r;
  r.x = f2bf(v.x); r.y = f2bf(v.y); r.z = f2bf(v.z); r.w = f2bf(v.w);
  ((ushort4*)Ebf)[i] = r;
}

// ---------------- K0b: build Bt[n][k] (bf16) from w1 (1536x768 row-major) --
// C[m][n] = sum_k E[m][k] * B[k][n];  n<768: B=w1[k][n]; n>=768: B=w1[768+k][n-768]
__global__ void k_bt(const float* __restrict__ w1, u16* __restrict__ Bt) {
  int idx = blockIdx.x * blockDim.x + threadIdx.x;
  if (idx >= GNN * HD) return;
  int n = idx / HD, k = idx % HD;
  int srow = k + ((n >= HD) ? HD : 0);
  int scol = (n >= HD) ? (n - HD) : n;
  Bt[idx] = f2bf(w1[(size_t)srow * HD + scol]);
}

// ---------------- K1: bf16 MFMA GEMM  PQ[40000][1536] = Ebf @ B -----------
// 128x128 tile, BK=32, 4 waves (2x2 of 64x64), 16x16x32 MFMA
__global__ __launch_bounds__(256) void k_gemm(const u16* __restrict__ A,
                                              const u16* __restrict__ B,
                                              u16* __restrict__ C) {
  __shared__ u16 sA[128 * 32];
  __shared__ u16 sB[128 * 32];
  const int tid  = threadIdx.x;
  const int lane = tid & 63;
  const int wv   = tid >> 6;
  const int bid  = blockIdx.x;
  const int nt   = bid % (GNN / 128);
  const int mt   = bid / (GNN / 128);
  const int tm   = mt * 128, tn = nt * 128;
  const int mr   = (wv >> 1) * 64;
  const int nc0  = (wv & 1) * 64;

  f32x4 acc[4][4];
#pragma unroll
  for (int i = 0; i < 4; ++i)
#pragma unroll
    for (int j = 0; j < 4; ++j) acc[i][j] = (f32x4){0.f, 0.f, 0.f, 0.f};

  for (int k0 = 0; k0 < HD; k0 += 32) {
    if (k0) __syncthreads();  // prior reads done before overwrite
#pragma unroll
    for (int c = 0; c < 2; ++c) {
      const int chunk = wv * 2 + c;
      const int off   = chunk * 1024 + lane * 16;  // byte offset into tile
      const int rloc  = off >> 6;                  // row (64B per 32-elem row)
      const int kloc  = (off & 63) >> 1;           // k elem offset
      int grA = tm + rloc; grA = (grA < NTREE) ? grA : (NTREE - 1);
      const u16* ga = A + ((size_t)grA * HD + k0 + kloc);
      __builtin_amdgcn_global_load_lds(
          (const __attribute__((address_space(1))) void*)ga,
          (__attribute__((address_space(3))) void*)((char*)sA + chunk * 1024),
          16, 0, 0);
      const u16* gb = B + ((size_t)(tn + rloc) * HD + k0 + kloc);
      __builtin_amdgcn_global_load_lds(
          (const __attribute__((address_space(1))) void*)gb,
          (__attribute__((address_space(3))) void*)((char*)sB + chunk * 1024),
          16, 0, 0);
    }
    __syncthreads();  // drains vmcnt(0): LDS tiles ready

    bfx8 af[4], bfr[4];
#pragma unroll
    for (int i = 0; i < 4; ++i)
      af[i] = *(const bfx8*)&sA[(mr + i * 16 + (lane & 15)) * 32 + (lane >> 4) * 8];
#pragma unroll
    for (int j = 0; j < 4; ++j)
      bfr[j] = *(const bfx8*)&sB[(nc0 + j * 16 + (lane & 15)) * 32 + (lane >> 4) * 8];
#pragma unroll
    for (int i = 0; i < 4; ++i)
#pragma unroll
      for (int j = 0; j < 4; ++j)
        acc[i][j] = __builtin_amdgcn_mfma_f32_16x16x32_bf16(af[i], bfr[j], acc[i][j], 0, 0, 0);
  }

  // epilogue: C/D layout col = lane&15, row = (lane>>4)*4 + r
  const int r0 = (lane >> 4) * 4, cc = lane & 15;
#pragma unroll
  for (int i = 0; i < 4; ++i) {
#pragma unroll
    for (int j = 0; j < 4; ++j) {
#pragma unroll
      for (int r = 0; r < 4; ++r) {
        int row = tm + mr + i * 16 + r0 + r;
        if (row < NTREE) {
          int col = tn + nc0 + j * 16 + cc;
          C[(size_t)row * GNN + col] = f2bf(acc[i][j][r]);
        }
      }
    }
  }
}

// ---------------- K2: scores + masked softmax + dag_emb -------------------
__global__ __launch_bounds__(256) void k_attn(const u16* __restrict__ PQ,
                                              const float* __restrict__ E,
                                              const float* __restrict__ b1,
                                              const float* __restrict__ w2,
                                              const float* __restrict__ b2,
                                              const float* __restrict__ masks,
                                              const int* __restrict__ leaves,
                                              const int* __restrict__ anc,
                                              float* __restrict__ dag) {
  const int n = blockIdx.x;
  const int tid = threadIdx.x, lane = tid & 63, wv = tid >> 6;
  __shared__ float sc[8];
  __shared__ float m_s[8];
  __shared__ int   an_s[8];
  __shared__ int   lv_s[8];
  if (tid < 8) {
    an_s[tid] = anc[n * 8 + tid];
    lv_s[tid] = leaves[n * 8 + tid];
    m_s[tid]  = masks[n * 8 + tid];
  }
  __syncthreads();

  for (int a = wv; a < 8; a += 4) {
    const int l = lv_s[a], an = an_s[a];
    const float mm = m_s[a];
    const u16* pr = PQ + (size_t)l * GNN;        // P part (cols 0..767)
    const u16* qr = PQ + (size_t)an * GNN + HD;  // Q part (cols 768..1535)
    const int d0 = lane * 12;
    float s = 0.f;
#pragma unroll
    for (int jj = 0; jj < 3; ++jj) {
      const int d = d0 + jj * 4;
      ushort4 pv = *(const ushort4*)(pr + d);
      ushort4 qv = *(const ushort4*)(qr + d);
      float4  bb = *(const float4*)(b1 + d);
      float4  ww = *(const float4*)(w2 + d);
      float v;
      v = fmaxf(mm * (bf2f(pv.x) + bf2f(qv.x)) + bb.x, 0.f); s += v * ww.x;
      v = fmaxf(mm * (bf2f(pv.y) + bf2f(qv.y)) + bb.y, 0.f); s += v * ww.y;
      v = fmaxf(mm * (bf2f(pv.z) + bf2f(qv.z)) + bb.z, 0.f); s += v * ww.z;
      v = fmaxf(mm * (bf2f(pv.w) + bf2f(qv.w)) + bb.w, 0.f); s += v * ww.w;
    }
#pragma unroll
    for (int off = 32; off > 0; off >>= 1) s += __shfl_down(s, off);
    if (lane == 0) sc[a] = s + b2[0] + (1.0f - mm) * VNEG;
  }
  __syncthreads();

  float mx = sc[0];
#pragma unroll
  for (int a = 1; a < 8; ++a) mx = fmaxf(mx, sc[a]);
  float ex[8], den = 0.f;
#pragma unroll
  for (int a = 0; a < 8; ++a) { ex[a] = expf(sc[a] - mx); den += ex[a]; }
  const float inv = 1.0f / den;
  float cf[8];
#pragma unroll
  for (int a = 0; a < 8; ++a) cf[a] = ex[a] * inv * m_s[a];

#pragma unroll
  for (int c = 0; c < 3; ++c) {
    const int d = tid + c * 256;
    float accv = 0.f;
#pragma unroll
    for (int a = 0; a < 8; ++a) accv += cf[a] * E[(size_t)an_s[a] * HD + d];
    dag[(size_t)n * HD + d] = accv;
  }
}

// ---------------- K3: gather dict + masked mean pooling -------------------
__global__ __launch_bounds__(256) void k_pool(const float* __restrict__ dag,
                                              const int* __restrict__ ids,
                                              const float* __restrict__ cm,
                                              float* __restrict__ pooled) {
  const int bv = blockIdx.x, tid = threadIdx.x;
  __shared__ int   id_s[48];
  __shared__ float cm_s[48];
  if (tid < 48) { id_s[tid] = ids[bv * 48 + tid]; cm_s[tid] = cm[bv * 48 + tid]; }
  __syncthreads();
  float cnt = 0.f;
  for (int m = 0; m < 48; ++m) cnt += cm_s[m];
  const float scale = 1.0f / fmaxf(cnt, 1.0f);
#pragma unroll
  for (int c = 0; c < 3; ++c) {
    const int d = tid + c * 256;
    float accv = 0.f;
    for (int m = 0; m < 48; ++m) {
      const int id = id_s[m];
      const float cv = cm_s[m];
      if (id > 0 && cv != 0.f) accv += cv * dag[(size_t)(id - 1) * HD + d];
    }
    pooled[(size_t)bv * HD + d] = accv * scale;
  }
}

// ---------------- K4: out = pooled @ wc + bc ------------------------------
__global__ __launch_bounds__(256) void k_out(const float* __restrict__ pooled,
                                             const float* __restrict__ wc,
                                             const float* __restrict__ bc,
                                             float* __restrict__ out) {
  const int b0 = blockIdx.x * TB;
  const int tid = threadIdx.x;
  __shared__ float pl[TB][HD];
  for (int i = tid; i < TB * HD; i += 256) pl[i / HD][i % HD] = pooled[(size_t)b0 * HD + i];
  __syncthreads();
  float a0[TB], a1[TB];
#pragma unroll
  for (int r = 0; r < TB; ++r) { a0[r] = 0.f; a1[r] = 0.f; }
  for (int h = 0; h < HD; ++h) {
    const float w0  = wc[(size_t)h * OUTD + tid];
    const float w1v = wc[(size_t)h * OUTD + tid + 256];
#pragma unroll
    for (int r = 0; r < TB; ++r) { const float p = pl[r][h]; a0[r] += p * w0; a1[r] += p * w1v; }
  }
  const float bc0 = bc[tid], bc1 = bc[tid + 256];
#pragma unroll
  for (int r = 0; r < TB; ++r) {
    out[(size_t)(b0 + r) * OUTD + tid]       = a0[r] + bc0;
    out[(size_t)(b0 + r) * OUTD + tid + 256] = a1[r] + bc1;
  }
}

extern "C" void kernel_launch(void* const* d_in, const int* in_sizes, int n_in,
                              void* d_out, int out_size, void* d_ws, size_t ws_size,
                              hipStream_t stream) {
  const float* E     = (const float*)d_in[0];
  const float* w1    = (const float*)d_in[1];
  const float* b1    = (const float*)d_in[2];
  const float* w2    = (const float*)d_in[3];
  const float* b2    = (const float*)d_in[4];
  const float* wc    = (const float*)d_in[5];
  const float* bc    = (const float*)d_in[6];
  const float* masks = (const float*)d_in[7];
  const float* cm    = (const float*)d_in[8];
  const int*   leaves = (const int*)d_in[9];
  const int*   anc    = (const int*)d_in[10];
  const int*   ids    = (const int*)d_in[11];
  float* out = (float*)d_out;

  if (n_in < 12) return;
  if (in_sizes[0] != NTREE * HD) return;
  if (out_size != NBV * OUTD) return;

  char* ws = (char*)d_ws;
  const size_t szEbf = (size_t)NTREE * HD * 2;
  const size_t szBt  = (size_t)GNN * HD * 2;
  const size_t szPQ  = (size_t)NTREE * GNN * 2;
  const size_t szDag = (size_t)NCODES * HD * 4;
  const size_t szPl  = (size_t)NBV * HD * 4;
  if (ws_size < szEbf + szBt + szPQ + szDag + szPl) return;  // ~209 MB needed

  u16*   Ebf    = (u16*)ws;            ws += szEbf;
  u16*   Bt     = (u16*)ws;            ws += szBt;
  u16*   PQ     = (u16*)ws;            ws += szPQ;
  float* dag    = (float*)ws;          ws += szDag;
  float* pooled = (float*)ws;          ws += szPl;

  const int n4 = NTREE * HD / 4;
  k_convE<<<(n4 + 255) / 256, 256, 0, stream>>>(E, Ebf, n4);
  k_bt<<<(GNN * HD + 255) / 256, 256, 0, stream>>>(w1, Bt);
  k_gemm<<<((NTREE + 127) / 128) * (GNN / 128), 256, 0, stream>>>(Ebf, Bt, PQ);
  k_attn<<<NCODES, 256, 0, stream>>>(PQ, E, b1, w2, b2, masks, leaves, anc, dag);
  k_pool<<<NBV, 256, 0, stream>>>(dag, ids, cm, pooled);
  k_out<<<NBV / TB, 256, 0, stream>>>(pooled, wc, bc, out);
}

// Round 2
// 329.203 us; speedup vs baseline: 1.0712x; 1.0712x over previous
//
#include <hip/hip_runtime.h>
#include <stdint.h>

typedef unsigned short u16;
typedef __bf16 bfx8 __attribute__((ext_vector_type(8)));
typedef float f32x4 __attribute__((ext_vector_type(4)));

#define HD 768
#define NTREE 40000
#define NCODES 10000
#define GNN 1536
#define OUTD 512
#define NBV 512
#define VNEG (-1e30f)
#define TB 4

// GEMM tiling
#define BM 256
#define BN 256
#define BK 32
#define NKT (HD / BK)  // 24
#define NMT ((NTREE + BM - 1) / BM)  // 157
#define NNT (GNN / BN)               // 6
#define GRID (NMT * NNT)             // 942
#define Q8 (GRID / 8)                // 117
#define R8 (GRID % 8)                // 6

#define WAITV(n) asm volatile("s_waitcnt vmcnt(" #n ")" ::: "memory")

__device__ __forceinline__ float bf2f(u16 u) {
  union { uint32_t i; float f; } v; v.i = ((uint32_t)u) << 16; return v.f;
}
__device__ __forceinline__ u16 f2bf(float f) {
  union { float fl; uint32_t i; } v; v.fl = f;
  uint32_t u = v.i;
  u += 0x7FFFu + ((u >> 16) & 1u);
  return (u16)(u >> 16);
}

// ---------------- K0a: fp32 -> bf16 convert of embed table ----------------
__global__ void k_convE(const float* __restrict__ E, u16* __restrict__ Ebf, int n4) {
  int i = blockIdx.x * blockDim.x + threadIdx.x;
  if (i >= n4) return;
  float4 v = ((const float4*)E)[i];
  ushort4 r;
  r.x = f2bf(v.x); r.y = f2bf(v.y); r.z = f2bf(v.z); r.w = f2bf(v.w);
  ((ushort4*)Ebf)[i] = r;
}

// ---------------- K0b: build Bt[n][k] (bf16) from w1 (1536x768 row-major) --
__global__ void k_bt(const float* __restrict__ w1, u16* __restrict__ Bt) {
  int idx = blockIdx.x * blockDim.x + threadIdx.x;
  if (idx >= GNN * HD) return;
  int n = idx / HD, k = idx % HD;
  int srow = k + ((n >= HD) ? HD : 0);
  int scol = (n >= HD) ? (n - HD) : n;
  Bt[idx] = f2bf(w1[(size_t)srow * HD + scol]);
}

// ---------------- K1: bf16 MFMA GEMM  PQ[40000][1536] = Ebf @ B -----------
// 256x256 tile, BK=32, 8 waves (2M x 4N), per-wave 128x64, 4-deep LDS ring,
// counted vmcnt(8) + single raw s_barrier per K-tile, T2 XOR swizzle, T5.
__global__ __launch_bounds__(512, 2) void k_gemm(const u16* __restrict__ A,
                                                 const u16* __restrict__ B,
                                                 u16* __restrict__ C) {
  __shared__ u16 sA[4 * BM * BK];  // 4 bufs x 16KB = 64KB
  __shared__ u16 sB[4 * BM * BK];  // 64KB

  const int tid  = threadIdx.x;
  const int lane = tid & 63;
  const int wv   = tid >> 6;          // 0..7
  const int wm   = wv >> 2;           // 0..1  (M half)
  const int wn   = wv & 3;            // 0..3  (N quarter)

  // bijective XCD swizzle, nt-minor so blocks on one XCD share the A panel
  const int orig = blockIdx.x;
  const int xcd = orig & 7, lin = orig >> 3;
  const int wg = (xcd < R8 ? xcd * (Q8 + 1) : R8 * (Q8 + 1) + (xcd - R8) * Q8) + lin;
  const int mt = wg / NNT, nt = wg % NNT;
  const int tm = mt * BM, tn = nt * BN;

  // ---- staging precompute: 2 A-loads + 2 B-loads per thread per K-tile ----
  const u16* gAp[2]; const u16* gBp[2];
  int ldsAoff[2], ldsBoff[2];
#pragma unroll
  for (int u = 0; u < 2; ++u) {
    const int idx = u * 512 + tid;       // 16B unit within tile (0..1023)
    const int r   = idx >> 2;            // row 0..255
    const int s   = idx & 3;             // physical 16B slot in row
    const int slc = s ^ ((r >> 1) & 3);  // logical k-chunk stored here (T2)
    int ra = tm + r; if (ra > NTREE - 1) ra = NTREE - 1;
    gAp[u] = A + (size_t)ra * HD + slc * 8;
    gBp[u] = B + (size_t)(tn + r) * HD + slc * 8;
    ldsAoff[u] = (u * 512 + wv * 64) * 16;  // wave-uniform byte base
    ldsBoff[u] = (u * 512 + wv * 64) * 16;
  }

#define STAGE(T, BUF)                                                          \
  do {                                                                         \
    const int _k0 = (T) * BK;                                                  \
    const int _bo = (BUF) * 16384;                                             \
    _Pragma("unroll") for (int u = 0; u < 2; ++u) {                            \
      __builtin_amdgcn_global_load_lds(                                        \
          (const __attribute__((address_space(1))) void*)(gAp[u] + _k0),       \
          (__attribute__((address_space(3))) void*)((char*)sA + _bo + ldsAoff[u]), \
          16, 0, 0);                                                           \
      __builtin_amdgcn_global_load_lds(                                        \
          (const __attribute__((address_space(1))) void*)(gBp[u] + _k0),       \
          (__attribute__((address_space(3))) void*)((char*)sB + _bo + ldsBoff[u]), \
          16, 0, 0);                                                           \
    }                                                                          \
  } while (0)

  f32x4 acc[8][4];
#pragma unroll
  for (int i = 0; i < 8; ++i)
#pragma unroll
    for (int j = 0; j < 4; ++j) acc[i][j] = (f32x4){0.f, 0.f, 0.f, 0.f};

  // fragment-read precompute (T2 swizzled slot; depends only on lane)
  const int lane15 = lane & 15;
  const int slq = ((lane >> 4) ^ ((lane15 >> 1) & 3)) * 8;  // u16 offset in row

  // prologue: stage tiles 0,1,2 into bufs 0,1,2 (12 load-insts in flight)
  STAGE(0, 0);
  STAGE(1, 1);
  STAGE(2, 2);

  for (int t = 0; t < NKT; ++t) {
    // counted drain: everything except the newest <=2 tiles (8 loads) is done
    if (t + 2 < NKT)      { WAITV(8); }
    else if (t + 1 < NKT) { WAITV(4); }
    else                  { WAITV(0); }
    __builtin_amdgcn_s_barrier();  // all waves: tile t staged; reads of t-1 drained

    if (t + 3 < NKT) STAGE(t + 3, (t + 3) & 3);  // overwrite buf[(t-1)&3]: safe

    const int bo = (t & 3) * (BM * BK);
    bfx8 af[8], bq[4];
#pragma unroll
    for (int i = 0; i < 8; ++i)
      af[i] = *(const bfx8*)&sA[bo + (wm * 128 + i * 16 + lane15) * BK + slq];
#pragma unroll
    for (int j = 0; j < 4; ++j)
      bq[j] = *(const bfx8*)&sB[bo + (wn * 64 + j * 16 + lane15) * BK + slq];

    __builtin_amdgcn_s_setprio(1);
#pragma unroll
    for (int i = 0; i < 8; ++i)
#pragma unroll
      for (int j = 0; j < 4; ++j)
        acc[i][j] = __builtin_amdgcn_mfma_f32_16x16x32_bf16(af[i], bq[j], acc[i][j], 0, 0, 0);
    __builtin_amdgcn_s_setprio(0);
  }

  // epilogue: D row = (lane>>4)*4 + r (M side), col = lane&15 (N side)
  const int r0 = (lane >> 4) * 4, cc = lane15;
#pragma unroll
  for (int i = 0; i < 8; ++i) {
#pragma unroll
    for (int j = 0; j < 4; ++j) {
#pragma unroll
      for (int r = 0; r < 4; ++r) {
        const int row = tm + wm * 128 + i * 16 + r0 + r;
        if (row < NTREE) {
          const int col = tn + wn * 64 + j * 16 + cc;
          C[(size_t)row * GNN + col] = f2bf(acc[i][j][r]);
        }
      }
    }
  }
#undef STAGE
}

// ---------------- K2: scores + masked softmax + dag_emb -------------------
__global__ __launch_bounds__(256) void k_attn(const u16* __restrict__ PQ,
                                              const u16* __restrict__ Ebf,
                                              const float* __restrict__ b1,
                                              const float* __restrict__ w2,
                                              const float* __restrict__ b2,
                                              const float* __restrict__ masks,
                                              const int* __restrict__ leaves,
                                              const int* __restrict__ anc,
                                              float* __restrict__ dag) {
  const int n = blockIdx.x;
  const int tid = threadIdx.x, lane = tid & 63, wv = tid >> 6;
  __shared__ float sc[8];
  __shared__ float m_s[8];
  __shared__ int   an_s[8];
  __shared__ int   lv_s[8];
  if (tid < 8) {
    an_s[tid] = anc[n * 8 + tid];
    lv_s[tid] = leaves[n * 8 + tid];
    m_s[tid]  = masks[n * 8 + tid];
  }
  __syncthreads();

  for (int a = wv; a < 8; a += 4) {
    const int l = lv_s[a], an = an_s[a];
    const float mm = m_s[a];
    const u16* pr = PQ + (size_t)l * GNN;        // P part (cols 0..767)
    const u16* qr = PQ + (size_t)an * GNN + HD;  // Q part (cols 768..1535)
    const int d0 = lane * 12;
    float s = 0.f;
#pragma unroll
    for (int jj = 0; jj < 3; ++jj) {
      const int d = d0 + jj * 4;
      ushort4 pv = *(const ushort4*)(pr + d);
      ushort4 qv = *(const ushort4*)(qr + d);
      float4  bb = *(const float4*)(b1 + d);
      float4  ww = *(const float4*)(w2 + d);
      float v;
      v = fmaxf(mm * (bf2f(pv.x) + bf2f(qv.x)) + bb.x, 0.f); s += v * ww.x;
      v = fmaxf(mm * (bf2f(pv.y) + bf2f(qv.y)) + bb.y, 0.f); s += v * ww.y;
      v = fmaxf(mm * (bf2f(pv.z) + bf2f(qv.z)) + bb.z, 0.f); s += v * ww.z;
      v = fmaxf(mm * (bf2f(pv.w) + bf2f(qv.w)) + bb.w, 0.f); s += v * ww.w;
    }
#pragma unroll
    for (int off = 32; off > 0; off >>= 1) s += __shfl_down(s, off);
    if (lane == 0) sc[a] = s + b2[0] + (1.0f - mm) * VNEG;
  }
  __syncthreads();

  float mx = sc[0];
#pragma unroll
  for (int a = 1; a < 8; ++a) mx = fmaxf(mx, sc[a]);
  float ex[8], den = 0.f;
#pragma unroll
  for (int a = 0; a < 8; ++a) { ex[a] = expf(sc[a] - mx); den += ex[a]; }
  const float inv = 1.0f / den;
  float cf[8];
#pragma unroll
  for (int a = 0; a < 8; ++a) cf[a] = ex[a] * inv * m_s[a];

#pragma unroll
  for (int c = 0; c < 3; ++c) {
    const int d = tid + c * 256;
    float accv = 0.f;
#pragma unroll
    for (int a = 0; a < 8; ++a) accv += cf[a] * bf2f(Ebf[(size_t)an_s[a] * HD + d]);
    dag[(size_t)n * HD + d] = accv;
  }
}

// ---------------- K3: gather dict + masked mean pooling -------------------
__global__ __launch_bounds__(256) void k_pool(const float* __restrict__ dag,
                                              const int* __restrict__ ids,
                                              const float* __restrict__ cm,
                                              float* __restrict__ pooled) {
  const int bv = blockIdx.x, tid = threadIdx.x;
  __shared__ int   id_s[48];
  __shared__ float cm_s[48];
  if (tid < 48) { id_s[tid] = ids[bv * 48 + tid]; cm_s[tid] = cm[bv * 48 + tid]; }
  __syncthreads();
  float cnt = 0.f;
  for (int m = 0; m < 48; ++m) cnt += cm_s[m];
  const float scale = 1.0f / fmaxf(cnt, 1.0f);
#pragma unroll
  for (int c = 0; c < 3; ++c) {
    const int d = tid + c * 256;
    float accv = 0.f;
    for (int m = 0; m < 48; ++m) {
      const int id = id_s[m];
      const float cv = cm_s[m];
      if (id > 0 && cv != 0.f) accv += cv * dag[(size_t)(id - 1) * HD + d];
    }
    pooled[(size_t)bv * HD + d] = accv * scale;
  }
}

// ---------------- K4: out = pooled @ wc + bc ------------------------------
__global__ __launch_bounds__(256) void k_out(const float* __restrict__ pooled,
                                             const float* __restrict__ wc,
                                             const float* __restrict__ bc,
                                             float* __restrict__ out) {
  const int b0 = blockIdx.x * TB;
  const int tid = threadIdx.x;
  __shared__ float pl[TB][HD];
  for (int i = tid; i < TB * HD; i += 256) pl[i / HD][i % HD] = pooled[(size_t)b0 * HD + i];
  __syncthreads();
  float a0[TB], a1[TB];
#pragma unroll
  for (int r = 0; r < TB; ++r) { a0[r] = 0.f; a1[r] = 0.f; }
  for (int h = 0; h < HD; ++h) {
    const float w0  = wc[(size_t)h * OUTD + tid];
    const float w1v = wc[(size_t)h * OUTD + tid + 256];
#pragma unroll
    for (int r = 0; r < TB; ++r) { const float p = pl[r][h]; a0[r] += p * w0; a1[r] += p * w1v; }
  }
  const float bc0 = bc[tid], bc1 = bc[tid + 256];
#pragma unroll
  for (int r = 0; r < TB; ++r) {
    out[(size_t)(b0 + r) * OUTD + tid]       = a0[r] + bc0;
    out[(size_t)(b0 + r) * OUTD + tid + 256] = a1[r] + bc1;
  }
}

extern "C" void kernel_launch(void* const* d_in, const int* in_sizes, int n_in,
                              void* d_out, int out_size, void* d_ws, size_t ws_size,
                              hipStream_t stream) {
  const float* E     = (const float*)d_in[0];
  const float* w1    = (const float*)d_in[1];
  const float* b1    = (const float*)d_in[2];
  const float* w2    = (const float*)d_in[3];
  const float* b2    = (const float*)d_in[4];
  const float* wc    = (const float*)d_in[5];
  const float* bc    = (const float*)d_in[6];
  const float* masks = (const float*)d_in[7];
  const float* cm    = (const float*)d_in[8];
  const int*   leaves = (const int*)d_in[9];
  const int*   anc    = (const int*)d_in[10];
  const int*   ids    = (const int*)d_in[11];
  float* out = (float*)d_out;

  if (n_in < 12) return;
  if (in_sizes[0] != NTREE * HD) return;
  if (out_size != NBV * OUTD) return;

  char* ws = (char*)d_ws;
  const size_t szEbf = (size_t)NTREE * HD * 2;
  const size_t szBt  = (size_t)GNN * HD * 2;
  const size_t szPQ  = (size_t)NTREE * GNN * 2;
  const size_t szDag = (size_t)NCODES * HD * 4;
  const size_t szPl  = (size_t)NBV * HD * 4;
  if (ws_size < szEbf + szBt + szPQ + szDag + szPl) return;  // ~209 MB

  u16*   Ebf    = (u16*)ws;            ws += szEbf;
  u16*   Bt     = (u16*)ws;            ws += szBt;
  u16*   PQ     = (u16*)ws;            ws += szPQ;
  float* dag    = (float*)ws;          ws += szDag;
  float* pooled = (float*)ws;          ws += szPl;

  const int n4 = NTREE * HD / 4;
  k_convE<<<(n4 + 255) / 256, 256, 0, stream>>>(E, Ebf, n4);
  k_bt<<<(GNN * HD + 255) / 256, 256, 0, stream>>>(w1, Bt);
  k_gemm<<<GRID, 512, 0, stream>>>(Ebf, Bt, PQ);
  k_attn<<<NCODES, 256, 0, stream>>>(PQ, Ebf, b1, w2, b2, masks, leaves, anc, dag);
  k_pool<<<NBV, 256, 0, stream>>>(dag, ids, cm, pooled);
  k_out<<<NBV / TB, 256, 0, stream>>>(pooled, wc, bc, out);
}

// Round 3
// 315.956 us; speedup vs baseline: 1.1161x; 1.0419x over previous
//
#include <hip/hip_runtime.h>
#include <stdint.h>

typedef unsigned short u16;
typedef __bf16 bfx8 __attribute__((ext_vector_type(8)));
typedef float f32x4 __attribute__((ext_vector_type(4)));

#define HD 768
#define NTREE 40000
#define NCODES 10000
#define GNN 1536
#define OUTD 512
#define NBV 512
#define VNEG (-1e30f)
#define TB 4

// GEMM tiling: 256x256 tile, BK=64, 8 waves of 256Mx32N each, 4 phases/K-tile
#define BM 256
#define BN 256
#define BK 64
#define NKT (HD / BK)                // 12
#define NMT ((NTREE + BM - 1) / BM)  // 157
#define NNT (GNN / BN)               // 6
#define GRID (NMT * NNT)             // 942
#define Q8 (GRID / 8)                // 117
#define R8 (GRID % 8)                // 6

#define WAITV(n) asm volatile("s_waitcnt vmcnt(" #n ")" ::: "memory")

__device__ __forceinline__ float bf2f(u16 u) {
  union { uint32_t i; float f; } v; v.i = ((uint32_t)u) << 16; return v.f;
}
__device__ __forceinline__ u16 f2bf(float f) {
  union { float fl; uint32_t i; } v; v.fl = f;
  uint32_t u = v.i;
  u += 0x7FFFu + ((u >> 16) & 1u);
  return (u16)(u >> 16);
}

// ---------------- K0a: fp32 -> bf16 convert of embed table ----------------
__global__ void k_convE(const float* __restrict__ E, u16* __restrict__ Ebf, int n4) {
  int i = blockIdx.x * blockDim.x + threadIdx.x;
  if (i >= n4) return;
  float4 v = ((const float4*)E)[i];
  ushort4 r;
  r.x = f2bf(v.x); r.y = f2bf(v.y); r.z = f2bf(v.z); r.w = f2bf(v.w);
  ((ushort4*)Ebf)[i] = r;
}

// ---------------- K0b: build Bt[n][k] (bf16) from w1 (1536x768 row-major) --
__global__ void k_bt(const float* __restrict__ w1, u16* __restrict__ Bt) {
  int idx = blockIdx.x * blockDim.x + threadIdx.x;
  if (idx >= GNN * HD) return;
  int n = idx / HD, k = idx % HD;
  int srow = k + ((n >= HD) ? HD : 0);
  int scol = (n >= HD) ? (n - HD) : n;
  Bt[idx] = f2bf(w1[(size_t)srow * HD + scol]);
}

// ---------------- K1: bf16 MFMA GEMM  PQ[40000][1536] = Ebf @ B -----------
// 4-phase-per-K-tile schedule (T3+T4), counted vmcnt, T2 (row&7) chunk-XOR
// swizzle, T5 setprio. LDS: A 2x32KB + B 2x32KB = 128KB.
// LDS byte map: A buf b at b*32768; B buf b at 65536 + b*32768.
// Within a tile: row r (0..255) at r*128 bytes; 16B chunk phys = logical^(r&7).
__global__ __launch_bounds__(512, 2) void k_gemm(const u16* __restrict__ A,
                                                 const u16* __restrict__ B,
                                                 u16* __restrict__ C) {
  __shared__ u16 lds[65536];  // 128 KB

  const int tid    = threadIdx.x;
  const int lane   = tid & 63;
  const int wn     = tid >> 6;       // 0..7: wave owns N cols wn*32..wn*32+31
  const int lane15 = lane & 15;
  const int g      = lane >> 4;      // 0..3: 16B chunk within K=32 step

  // bijective XCD swizzle, nt-minor (blocks on one XCD share the A panel)
  const int orig = blockIdx.x;
  const int xcd = orig & 7, lin = orig >> 3;
  const int wg = (xcd < R8 ? xcd * (Q8 + 1) : R8 * (Q8 + 1) + (xcd - R8) * Q8) + lin;
  const int mt = wg / NNT, nt = wg % NNT;
  const int tm = mt * BM, tn = nt * BN;

  // staging source pointers (pre-swizzled global source, rule 21)
  const u16* aSrc[2][2];  // [u][mh]
  const u16* bSrc[2][2];  // [u][nh]
#pragma unroll
  for (int u = 0; u < 2; ++u) {
    const int o    = u * 8192 + tid * 16;          // byte in 16KB half
    const int rloc = o >> 7;                        // local row 0..127
    const int c    = ((o >> 4) & 7) ^ (rloc & 7);   // logical 16B chunk
#pragma unroll
    for (int h = 0; h < 2; ++h) {
      int ra = tm + h * 128 + rloc; if (ra > NTREE - 1) ra = NTREE - 1;
      aSrc[u][h] = A + (size_t)ra * HD + c * 8;
      bSrc[u][h] = B + (size_t)(tn + h * 128 + rloc) * HD + c * 8;
    }
  }

#define STAGE_A(MH, NB, TT) do {                                               \
    _Pragma("unroll") for (int u = 0; u < 2; ++u)                              \
      __builtin_amdgcn_global_load_lds(                                        \
        (const __attribute__((address_space(1))) void*)(aSrc[u][MH] + (TT) * BK), \
        (__attribute__((address_space(3))) void*)((char*)lds + (NB) * 32768 +  \
            (MH) * 16384 + u * 8192 + tid * 16),                               \
        16, 0, 0);                                                             \
  } while (0)

#define STAGE_B(NH, NB, TT) do {                                               \
    _Pragma("unroll") for (int u = 0; u < 2; ++u)                              \
      __builtin_amdgcn_global_load_lds(                                        \
        (const __attribute__((address_space(1))) void*)(bSrc[u][NH] + (TT) * BK), \
        (__attribute__((address_space(3))) void*)((char*)lds + 65536 +         \
            (NB) * 32768 + (NH) * 16384 + u * 8192 + tid * 16),                \
        16, 0, 0);                                                             \
  } while (0)

  f32x4 acc[16][2];
#pragma unroll
  for (int i = 0; i < 16; ++i) {
    acc[i][0] = (f32x4){0.f, 0.f, 0.f, 0.f};
    acc[i][1] = (f32x4){0.f, 0.f, 0.f, 0.f};
  }

  // swizzled read column offset (u16 elems) per k-step
  int colz[2];
  colz[0] = ((0 * 4 + g) ^ (lane15 & 7)) * 8;
  colz[1] = ((1 * 4 + g) ^ (lane15 & 7)) * 8;
  const int rbase = lane15 * 64;  // u16 elems per row stride 64

  bfx8 aF[8], bF[2][2];

// phase: reads (A[mh][ks] 8x b128, B[ks] 2x b128 on mh==0) | stage | barrier |
//        lgkmcnt(0) | 16 MFMA (setprio) | drain | barrier
#define PHASE(MH, KS, STAGE_STMT, DRAIN_STMT)                                  \
  {                                                                            \
    const int _az = bA + (MH) * 8192 + rbase + colz[KS];                       \
    _Pragma("unroll") for (int i = 0; i < 8; ++i)                              \
      aF[i] = *(const bfx8*)&lds[_az + i * 1024];                              \
    if ((MH) == 0) {                                                           \
      const int _bz = bB + wn * 2048 + rbase + colz[KS];                       \
      bF[KS][0] = *(const bfx8*)&lds[_bz];                                     \
      bF[KS][1] = *(const bfx8*)&lds[_bz + 1024];                              \
    }                                                                          \
    STAGE_STMT;                                                                \
    __builtin_amdgcn_s_barrier();                                              \
    asm volatile("s_waitcnt lgkmcnt(0)" ::: "memory");                         \
    __builtin_amdgcn_sched_barrier(0);                                         \
    __builtin_amdgcn_s_setprio(1);                                             \
    _Pragma("unroll") for (int i = 0; i < 8; ++i) {                            \
      acc[(MH) * 8 + i][0] = __builtin_amdgcn_mfma_f32_16x16x32_bf16(          \
          aF[i], bF[KS][0], acc[(MH) * 8 + i][0], 0, 0, 0);                    \
      acc[(MH) * 8 + i][1] = __builtin_amdgcn_mfma_f32_16x16x32_bf16(          \
          aF[i], bF[KS][1], acc[(MH) * 8 + i][1], 0, 0, 0);                    \
    }                                                                          \
    __builtin_amdgcn_s_setprio(0);                                             \
    DRAIN_STMT;                                                                \
    __builtin_amdgcn_s_barrier();                                              \
  }

  // prologue: stage tile 0 into buf 0 (order B-lo,B-hi,A-lo,A-hi = 8 loads),
  // drain all but the newest half (A-hi), barrier.
  STAGE_B(0, 0, 0);
  STAGE_B(1, 0, 0);
  STAGE_A(0, 0, 0);
  STAGE_A(1, 0, 0);
  WAITV(2);
  __builtin_amdgcn_s_barrier();

  for (int t = 0; t < NKT; ++t) {
    const int cur = t & 1, nb = cur ^ 1;
    const int bA = cur * 16384;           // u16 index of A buf
    const int bB = 32768 + cur * 16384;   // u16 index of B buf
    const bool more = (t + 1 < NKT);

    // p0: (A-lo, ks0). stage B-lo(t+1).
    PHASE(0, 0, if (more) STAGE_B(0, nb, t + 1), );
    // p1: (A-lo, ks1). stage B-hi(t+1). drain for A-hi(t) read at p2.
    PHASE(0, 1, if (more) STAGE_B(1, nb, t + 1),
          if (t == NKT - 1) { WAITV(0); } else { WAITV(4); });
    // p2: (A-hi, ks0). stage A-lo(t+1).
    PHASE(1, 0, if (more) STAGE_A(0, nb, t + 1), );
    // p3: (A-hi, ks1). stage A-hi(t+1). drain for B-lo/B-hi/A-lo(t+1) at p0.
    PHASE(1, 1, if (more) STAGE_A(1, nb, t + 1), WAITV(2));
  }

  // epilogue: D row = (lane>>4)*4 + rr (M side), col = lane&15 (N side)
  const int r0 = (lane >> 4) * 4, cc = lane15;
#pragma unroll
  for (int mf = 0; mf < 16; ++mf) {
#pragma unroll
    for (int j = 0; j < 2; ++j) {
#pragma unroll
      for (int rr = 0; rr < 4; ++rr) {
        const int row = tm + mf * 16 + r0 + rr;
        if (row < NTREE) {
          const int col = tn + wn * 32 + j * 16 + cc;
          C[(size_t)row * GNN + col] = f2bf(acc[mf][j][rr]);
        }
      }
    }
  }
#undef PHASE
#undef STAGE_A
#undef STAGE_B
}

// ---------------- K2: scores + masked softmax + dag_emb -------------------
// mask is binary; masked pairs contribute exactly 0 (exp(VNEG)=0 and attn*m=0)
// so skip their P/Q reads and their E-gather entirely.
__global__ __launch_bounds__(256) void k_attn(const u16* __restrict__ PQ,
                                              const u16* __restrict__ Ebf,
                                              const float* __restrict__ b1,
                                              const float* __restrict__ w2,
                                              const float* __restrict__ b2,
                                              const float* __restrict__ masks,
                                              const int* __restrict__ leaves,
                                              const int* __restrict__ anc,
                                              float* __restrict__ dag) {
  const int n = blockIdx.x;
  const int tid = threadIdx.x, lane = tid & 63, wv = tid >> 6;
  __shared__ float sc[8];
  __shared__ float m_s[8];
  __shared__ int   an_s[8];
  __shared__ int   lv_s[8];
  if (tid < 8) {
    an_s[tid] = anc[n * 8 + tid];
    lv_s[tid] = leaves[n * 8 + tid];
    m_s[tid]  = masks[n * 8 + tid];
  }
  __syncthreads();

  for (int a = wv; a < 8; a += 4) {
    const float mm = m_s[a];
    if (mm == 0.f) {
      if (lane == 0) sc[a] = VNEG;
      continue;
    }
    const int l = lv_s[a], an = an_s[a];
    const u16* pr = PQ + (size_t)l * GNN;        // P part (cols 0..767)
    const u16* qr = PQ + (size_t)an * GNN + HD;  // Q part (cols 768..1535)
    const int d0 = lane * 12;
    float s = 0.f;
#pragma unroll
    for (int jj = 0; jj < 3; ++jj) {
      const int d = d0 + jj * 4;
      ushort4 pv = *(const ushort4*)(pr + d);
      ushort4 qv = *(const ushort4*)(qr + d);
      float4  bb = *(const float4*)(b1 + d);
      float4  ww = *(const float4*)(w2 + d);
      float v;
      v = fmaxf(bf2f(pv.x) + bf2f(qv.x) + bb.x, 0.f); s += v * ww.x;
      v = fmaxf(bf2f(pv.y) + bf2f(qv.y) + bb.y, 0.f); s += v * ww.y;
      v = fmaxf(bf2f(pv.z) + bf2f(qv.z) + bb.z, 0.f); s += v * ww.z;
      v = fmaxf(bf2f(pv.w) + bf2f(qv.w) + bb.w, 0.f); s += v * ww.w;
    }
#pragma unroll
    for (int off = 32; off > 0; off >>= 1) s += __shfl_down(s, off);
    if (lane == 0) sc[a] = s + b2[0];
  }
  __syncthreads();

  float mx = sc[0];
#pragma unroll
  for (int a = 1; a < 8; ++a) mx = fmaxf(mx, sc[a]);
  float ex[8], den = 0.f;
#pragma unroll
  for (int a = 0; a < 8; ++a) { ex[a] = expf(sc[a] - mx); den += ex[a]; }
  const float inv = 1.0f / den;
  float cf[8];
#pragma unroll
  for (int a = 0; a < 8; ++a) cf[a] = ex[a] * inv * m_s[a];

#pragma unroll
  for (int c = 0; c < 3; ++c) {
    const int d = tid + c * 256;
    float accv = 0.f;
#pragma unroll
    for (int a = 0; a < 8; ++a) {
      const float cfa = cf[a];
      if (cfa != 0.f) accv += cfa * bf2f(Ebf[(size_t)an_s[a] * HD + d]);
    }
    dag[(size_t)n * HD + d] = accv;
  }
}

// ---------------- K3: gather dict + masked mean pooling -------------------
__global__ __launch_bounds__(256) void k_pool(const float* __restrict__ dag,
                                              const int* __restrict__ ids,
                                              const float* __restrict__ cm,
                                              float* __restrict__ pooled) {
  const int bv = blockIdx.x, tid = threadIdx.x;
  __shared__ int   id_s[48];
  __shared__ float cm_s[48];
  if (tid < 48) { id_s[tid] = ids[bv * 48 + tid]; cm_s[tid] = cm[bv * 48 + tid]; }
  __syncthreads();
  float cnt = 0.f;
  for (int m = 0; m < 48; ++m) cnt += cm_s[m];
  const float scale = 1.0f / fmaxf(cnt, 1.0f);
#pragma unroll
  for (int c = 0; c < 3; ++c) {
    const int d = tid + c * 256;
    float accv = 0.f;
    for (int m = 0; m < 48; ++m) {
      const int id = id_s[m];
      const float cv = cm_s[m];
      if (id > 0 && cv != 0.f) accv += cv * dag[(size_t)(id - 1) * HD + d];
    }
    pooled[(size_t)bv * HD + d] = accv * scale;
  }
}

// ---------------- K4: out = pooled @ wc + bc ------------------------------
__global__ __launch_bounds__(256) void k_out(const float* __restrict__ pooled,
                                             const float* __restrict__ wc,
                                             const float* __restrict__ bc,
                                             float* __restrict__ out) {
  const int b0 = blockIdx.x * TB;
  const int tid = threadIdx.x;
  __shared__ float pl[TB][HD];
  for (int i = tid; i < TB * HD; i += 256) pl[i / HD][i % HD] = pooled[(size_t)b0 * HD + i];
  __syncthreads();
  float a0[TB], a1[TB];
#pragma unroll
  for (int r = 0; r < TB; ++r) { a0[r] = 0.f; a1[r] = 0.f; }
  for (int h = 0; h < HD; ++h) {
    const float w0  = wc[(size_t)h * OUTD + tid];
    const float w1v = wc[(size_t)h * OUTD + tid + 256];
#pragma unroll
    for (int r = 0; r < TB; ++r) { const float p = pl[r][h]; a0[r] += p * w0; a1[r] += p * w1v; }
  }
  const float bc0 = bc[tid], bc1 = bc[tid + 256];
#pragma unroll
  for (int r = 0; r < TB; ++r) {
    out[(size_t)(b0 + r) * OUTD + tid]       = a0[r] + bc0;
    out[(size_t)(b0 + r) * OUTD + tid + 256] = a1[r] + bc1;
  }
}

extern "C" void kernel_launch(void* const* d_in, const int* in_sizes, int n_in,
                              void* d_out, int out_size, void* d_ws, size_t ws_size,
                              hipStream_t stream) {
  const float* E     = (const float*)d_in[0];
  const float* w1    = (const float*)d_in[1];
  const float* b1    = (const float*)d_in[2];
  const float* w2    = (const float*)d_in[3];
  const float* b2    = (const float*)d_in[4];
  const float* wc    = (const float*)d_in[5];
  const float* bc    = (const float*)d_in[6];
  const float* masks = (const float*)d_in[7];
  const float* cm    = (const float*)d_in[8];
  const int*   leaves = (const int*)d_in[9];
  const int*   anc    = (const int*)d_in[10];
  const int*   ids    = (const int*)d_in[11];
  float* out = (float*)d_out;

  if (n_in < 12) return;
  if (in_sizes[0] != NTREE * HD) return;
  if (out_size != NBV * OUTD) return;

  char* ws = (char*)d_ws;
  const size_t szEbf = (size_t)NTREE * HD * 2;
  const size_t szBt  = (size_t)GNN * HD * 2;
  const size_t szPQ  = (size_t)NTREE * GNN * 2;
  const size_t szDag = (size_t)NCODES * HD * 4;
  const size_t szPl  = (size_t)NBV * HD * 4;
  if (ws_size < szEbf + szBt + szPQ + szDag + szPl) return;  // ~209 MB

  u16*   Ebf    = (u16*)ws;            ws += szEbf;
  u16*   Bt     = (u16*)ws;            ws += szBt;
  u16*   PQ     = (u16*)ws;            ws += szPQ;
  float* dag    = (float*)ws;          ws += szDag;
  float* pooled = (float*)ws;          ws += szPl;

  const int n4 = NTREE * HD / 4;
  k_convE<<<(n4 + 255) / 256, 256, 0, stream>>>(E, Ebf, n4);
  k_bt<<<(GNN * HD + 255) / 256, 256, 0, stream>>>(w1, Bt);
  k_gemm<<<GRID, 512, 0, stream>>>(Ebf, Bt, PQ);
  k_attn<<<NCODES, 256, 0, stream>>>(PQ, Ebf, b1, w2, b2, masks, leaves, anc, dag);
  k_pool<<<NBV, 256, 0, stream>>>(dag, ids, cm, pooled);
  k_out<<<NBV / TB, 256, 0, stream>>>(pooled, wc, bc, out);
}

// Round 4
// 301.664 us; speedup vs baseline: 1.1690x; 1.0474x over previous
//
#include <hip/hip_runtime.h>
#include <stdint.h>

typedef unsigned short u16;
typedef __bf16 bfx8 __attribute__((ext_vector_type(8)));
typedef float f32x4 __attribute__((ext_vector_type(4)));
typedef u16 u16x8 __attribute__((ext_vector_type(8)));

#define HD 768
#define NTREE 40000
#define NCODES 10000
#define GNN 1536
#define OUTD 512
#define NBV 512
#define VNEG (-1e30f)
#define TB 4

// GEMM tiling: 256x256 tile, BK=64, 8 waves as 2M x 4N (128x64 per wave),
// 4 phases per K-tile (phase = M-quadrant x ks), 2-deep LDS dbuf.
#define BM 256
#define BN 256
#define BK 64
#define NKT (HD / BK)                // 12
#define NMT ((NTREE + BM - 1) / BM)  // 157
#define NNT (GNN / BN)               // 6
#define GRID (NMT * NNT)             // 942
#define Q8 (GRID / 8)                // 117
#define R8 (GRID % 8)                // 6

#define WAITV(n) asm volatile("s_waitcnt vmcnt(" #n ")" ::: "memory")

__device__ __forceinline__ float bf2f(u16 u) {
  union { uint32_t i; float f; } v; v.i = ((uint32_t)u) << 16; return v.f;
}
__device__ __forceinline__ u16 f2bf(float f) {
  union { float fl; uint32_t i; } v; v.fl = f;
  uint32_t u = v.i;
  u += 0x7FFFu + ((u >> 16) & 1u);
  return (u16)(u >> 16);
}

// ---------------- K0a: fp32 -> bf16 convert of embed table ----------------
__global__ void k_convE(const float* __restrict__ E, u16* __restrict__ Ebf, int n4) {
  int i = blockIdx.x * blockDim.x + threadIdx.x;
  if (i >= n4) return;
  float4 v = ((const float4*)E)[i];
  ushort4 r;
  r.x = f2bf(v.x); r.y = f2bf(v.y); r.z = f2bf(v.z); r.w = f2bf(v.w);
  ((ushort4*)Ebf)[i] = r;
}

// ---------------- K0b: build Bt[n][k] (bf16) from w1 (1536x768 row-major) --
__global__ void k_bt(const float* __restrict__ w1, u16* __restrict__ Bt) {
  int idx = blockIdx.x * blockDim.x + threadIdx.x;
  if (idx >= GNN * HD) return;
  int n = idx / HD, k = idx % HD;
  int srow = k + ((n >= HD) ? HD : 0);
  int scol = (n >= HD) ? (n - HD) : n;
  Bt[idx] = f2bf(w1[(size_t)srow * HD + scol]);
}

// ---------------- K1: bf16 MFMA GEMM  PQ[40000][1536] = Ebf @ B -----------
// LDS byte map: A buf b at b*32768; B buf b at 65536 + b*32768.
// Within a tile: row r (0..255) at r*128 bytes; 16B chunk phys = logical^(r&7).
__global__ __launch_bounds__(512, 2) void k_gemm(const u16* __restrict__ A,
                                                 const u16* __restrict__ B,
                                                 u16* __restrict__ C) {
  __shared__ u16 lds[65536];  // 128 KB

  const int tid    = threadIdx.x;
  const int lane   = tid & 63;
  const int wv     = tid >> 6;       // 0..7
  const int wm     = wv >> 2;        // 0..1: wave's M half (rows wm*128..+127)
  const int wn2    = wv & 3;         // 0..3: wave's N strip (cols wn2*64..+63)
  const int lane15 = lane & 15;
  const int g      = lane >> 4;      // 0..3: 16B chunk within K=32 step

  // bijective XCD swizzle, nt-minor (blocks on one XCD share the A panel)
  const int orig = blockIdx.x;
  const int xcd = orig & 7, lin = orig >> 3;
  const int wg = (xcd < R8 ? xcd * (Q8 + 1) : R8 * (Q8 + 1) + (xcd - R8) * Q8) + lin;
  const int mt = wg / NNT, nt = wg % NNT;
  const int tm = mt * BM, tn = nt * BN;

  // staging source pointers (pre-swizzled global source, rule 21)
  const u16* aSrc[2][2];  // [u][half]
  const u16* bSrc[2][2];
#pragma unroll
  for (int u = 0; u < 2; ++u) {
    const int o    = u * 8192 + tid * 16;          // byte in 16KB half
    const int rloc = o >> 7;                        // local row 0..127
    const int c    = ((o >> 4) & 7) ^ (rloc & 7);   // logical 16B chunk
#pragma unroll
    for (int h = 0; h < 2; ++h) {
      int ra = tm + h * 128 + rloc; if (ra > NTREE - 1) ra = NTREE - 1;
      aSrc[u][h] = A + (size_t)ra * HD + c * 8;
      bSrc[u][h] = B + (size_t)(tn + h * 128 + rloc) * HD + c * 8;
    }
  }

#define STAGE_A(MH, NB, TT) do {                                               \
    _Pragma("unroll") for (int u = 0; u < 2; ++u)                              \
      __builtin_amdgcn_global_load_lds(                                        \
        (const __attribute__((address_space(1))) void*)(aSrc[u][MH] + (TT) * BK), \
        (__attribute__((address_space(3))) void*)((char*)lds + (NB) * 32768 +  \
            (MH) * 16384 + u * 8192 + tid * 16),                               \
        16, 0, 0);                                                             \
  } while (0)

#define STAGE_B(NH, NB, TT) do {                                               \
    _Pragma("unroll") for (int u = 0; u < 2; ++u)                              \
      __builtin_amdgcn_global_load_lds(                                        \
        (const __attribute__((address_space(1))) void*)(bSrc[u][NH] + (TT) * BK), \
        (__attribute__((address_space(3))) void*)((char*)lds + 65536 +         \
            (NB) * 32768 + (NH) * 16384 + u * 8192 + tid * 16),                \
        16, 0, 0);                                                             \
  } while (0)

  f32x4 acc[8][4];
#pragma unroll
  for (int i = 0; i < 8; ++i)
#pragma unroll
    for (int j = 0; j < 4; ++j) acc[i][j] = (f32x4){0.f, 0.f, 0.f, 0.f};

  // swizzled read column offset (u16 elems) per k-step; row&7 == lane15&7
  int colz[2];
  colz[0] = ((0 * 4 + g) ^ (lane15 & 7)) * 8;
  colz[1] = ((1 * 4 + g) ^ (lane15 & 7)) * 8;
  const int aBase = (wm * 128 + lane15) * 64;  // u16 elems, row stride 64
  const int bBase = (wn2 * 64 + lane15) * 64;

  bfx8 aF[4], bF[4];

// phase (MH = M-quadrant within wave's half, KS = k-step):
// reads 4 A-frags (+4 B-frags when MH==0) | stage | barrier | lgkm(0) |
// 16 MFMA (setprio) | drain | barrier
#define PHASE(MH, KS, STAGE_STMT, DRAIN_STMT)                                  \
  {                                                                            \
    const int _az = bA + aBase + (MH) * 4096 + colz[KS];                       \
    _Pragma("unroll") for (int i = 0; i < 4; ++i)                              \
      aF[i] = *(const bfx8*)&lds[_az + i * 1024];                              \
    if ((MH) == 0) {                                                           \
      const int _bz = bB + bBase + colz[KS];                                   \
      _Pragma("unroll") for (int j = 0; j < 4; ++j)                            \
        bF[j] = *(const bfx8*)&lds[_bz + j * 1024];                            \
    }                                                                          \
    STAGE_STMT;                                                                \
    __builtin_amdgcn_s_barrier();                                              \
    asm volatile("s_waitcnt lgkmcnt(0)" ::: "memory");                         \
    __builtin_amdgcn_sched_barrier(0);                                         \
    __builtin_amdgcn_s_setprio(1);                                             \
    _Pragma("unroll") for (int i = 0; i < 4; ++i)                              \
      _Pragma("unroll") for (int j = 0; j < 4; ++j)                            \
        acc[(MH) * 4 + i][j] = __builtin_amdgcn_mfma_f32_16x16x32_bf16(        \
            aF[i], bF[j], acc[(MH) * 4 + i][j], 0, 0, 0);                      \
    __builtin_amdgcn_s_setprio(0);                                             \
    DRAIN_STMT;                                                                \
    __builtin_amdgcn_s_barrier();                                              \
  }

  // prologue: stage tile 0 into buf 0, drain, barrier
  STAGE_A(0, 0, 0);
  STAGE_A(1, 0, 0);
  STAGE_B(0, 0, 0);
  STAGE_B(1, 0, 0);
  WAITV(0);
  __builtin_amdgcn_s_barrier();

  for (int t = 0; t < NKT; ++t) {
    const int cur = t & 1, nb = cur ^ 1;
    const int bA = cur * 16384;           // u16 index of A buf
    const int bB = 32768 + cur * 16384;   // u16 index of B buf
    const bool more = (t + 1 < NKT);

    // p0: quadrant 0, ks0 (reads A+B). stage A halves of t+1.
    PHASE(0, 0, if (more) { STAGE_A(0, nb, t + 1); STAGE_A(1, nb, t + 1); }, );
    // p1: quadrant 1, ks0 (reads A, reuses B). stage B halves of t+1.
    PHASE(1, 0, if (more) { STAGE_B(0, nb, t + 1); STAGE_B(1, nb, t + 1); }, );
    // p2: quadrant 0, ks1 (reads A+B).
    PHASE(0, 1, , );
    // p3: quadrant 1, ks1 (reads A). drain all 8 staged loads (2-3 phase cover).
    PHASE(1, 1, , WAITV(0));
  }

  // epilogue: D row = (lane>>4)*4 + rr (M side), col = lane&15 (N side)
  const int r0 = (lane >> 4) * 4, cc = lane15;
#pragma unroll
  for (int mf = 0; mf < 8; ++mf) {
#pragma unroll
    for (int nf = 0; nf < 4; ++nf) {
#pragma unroll
      for (int rr = 0; rr < 4; ++rr) {
        const int row = tm + wm * 128 + mf * 16 + r0 + rr;
        if (row < NTREE) {
          const int col = tn + wn2 * 64 + nf * 16 + cc;
          C[(size_t)row * GNN + col] = f2bf(acc[mf][nf][rr]);
        }
      }
    }
  }
#undef PHASE
#undef STAGE_A
#undef STAGE_B
}

// ---------------- K2: scores + masked softmax + dag_emb -------------------
// 8 waves, one (n,a) pair per wave; b128 P/Q loads; masked pairs skipped.
__device__ __forceinline__ float dot8(const u16* pr, const u16* qr,
                                      const float* b1, const float* w2, int d) {
  u16x8 pv = *(const u16x8*)(pr + d);
  u16x8 qv = *(const u16x8*)(qr + d);
  float4 bb0 = *(const float4*)(b1 + d);
  float4 bb1 = *(const float4*)(b1 + d + 4);
  float4 ww0 = *(const float4*)(w2 + d);
  float4 ww1 = *(const float4*)(w2 + d + 4);
  float s = 0.f, v;
  v = fmaxf(bf2f(pv[0]) + bf2f(qv[0]) + bb0.x, 0.f); s += v * ww0.x;
  v = fmaxf(bf2f(pv[1]) + bf2f(qv[1]) + bb0.y, 0.f); s += v * ww0.y;
  v = fmaxf(bf2f(pv[2]) + bf2f(qv[2]) + bb0.z, 0.f); s += v * ww0.z;
  v = fmaxf(bf2f(pv[3]) + bf2f(qv[3]) + bb0.w, 0.f); s += v * ww0.w;
  v = fmaxf(bf2f(pv[4]) + bf2f(qv[4]) + bb1.x, 0.f); s += v * ww1.x;
  v = fmaxf(bf2f(pv[5]) + bf2f(qv[5]) + bb1.y, 0.f); s += v * ww1.y;
  v = fmaxf(bf2f(pv[6]) + bf2f(qv[6]) + bb1.z, 0.f); s += v * ww1.z;
  v = fmaxf(bf2f(pv[7]) + bf2f(qv[7]) + bb1.w, 0.f); s += v * ww1.w;
  return s;
}

__global__ __launch_bounds__(512) void k_attn(const u16* __restrict__ PQ,
                                              const u16* __restrict__ Ebf,
                                              const float* __restrict__ b1,
                                              const float* __restrict__ w2,
                                              const float* __restrict__ b2,
                                              const float* __restrict__ masks,
                                              const int* __restrict__ leaves,
                                              const int* __restrict__ anc,
                                              float* __restrict__ dag) {
  const int n = blockIdx.x;
  const int tid = threadIdx.x, lane = tid & 63, wv = tid >> 6;
  __shared__ float sc[8];
  __shared__ float m_s[8];
  __shared__ int   an_s[8];
  __shared__ int   lv_s[8];
  if (tid < 8) {
    an_s[tid] = anc[n * 8 + tid];
    lv_s[tid] = leaves[n * 8 + tid];
    m_s[tid]  = masks[n * 8 + tid];
  }
  __syncthreads();

  {
    const int a = wv;
    const float mm = m_s[a];
    if (mm == 0.f) {
      if (lane == 0) sc[a] = VNEG;
    } else {
      const int l = lv_s[a], an = an_s[a];
      const u16* pr = PQ + (size_t)l * GNN;        // P part (cols 0..767)
      const u16* qr = PQ + (size_t)an * GNN + HD;  // Q part (cols 768..1535)
      float s = dot8(pr, qr, b1, w2, lane * 8);
      if (lane < 32) s += dot8(pr, qr, b1, w2, 512 + lane * 8);
#pragma unroll
      for (int off = 32; off > 0; off >>= 1) s += __shfl_down(s, off);
      if (lane == 0) sc[a] = s + b2[0];
    }
  }
  __syncthreads();

  float mx = sc[0];
#pragma unroll
  for (int a = 1; a < 8; ++a) mx = fmaxf(mx, sc[a]);
  float ex[8], den = 0.f;
#pragma unroll
  for (int a = 0; a < 8; ++a) { ex[a] = expf(sc[a] - mx); den += ex[a]; }
  const float inv = 1.0f / den;
  float cf[8];
#pragma unroll
  for (int a = 0; a < 8; ++a) cf[a] = ex[a] * inv * m_s[a];

  {
    int d = tid;
    float accv = 0.f;
#pragma unroll
    for (int a = 0; a < 8; ++a) {
      const float cfa = cf[a];
      if (cfa != 0.f) accv += cfa * bf2f(Ebf[(size_t)an_s[a] * HD + d]);
    }
    dag[(size_t)n * HD + d] = accv;
  }
  if (tid < 256) {
    const int d = 512 + tid;
    float accv = 0.f;
#pragma unroll
    for (int a = 0; a < 8; ++a) {
      const float cfa = cf[a];
      if (cfa != 0.f) accv += cfa * bf2f(Ebf[(size_t)an_s[a] * HD + d]);
    }
    dag[(size_t)n * HD + d] = accv;
  }
}

// ---------------- K3: gather dict + masked mean pooling (float4) ----------
__global__ __launch_bounds__(256) void k_pool(const float* __restrict__ dag,
                                              const int* __restrict__ ids,
                                              const float* __restrict__ cm,
                                              float* __restrict__ pooled) {
  const int bv = blockIdx.x, tid = threadIdx.x;
  __shared__ int   id_s[48];
  __shared__ float cm_s[48];
  if (tid < 48) { id_s[tid] = ids[bv * 48 + tid]; cm_s[tid] = cm[bv * 48 + tid]; }
  __syncthreads();
  float cnt = 0.f;
  for (int m = 0; m < 48; ++m) cnt += cm_s[m];
  const float scale = 1.0f / fmaxf(cnt, 1.0f);
  if (tid < 192) {
    float4 accv = make_float4(0.f, 0.f, 0.f, 0.f);
    for (int m = 0; m < 48; ++m) {
      const int id = id_s[m];
      const float cv = cm_s[m];
      if (id > 0 && cv != 0.f) {
        float4 v = *(const float4*)(dag + (size_t)(id - 1) * HD + tid * 4);
        accv.x += cv * v.x; accv.y += cv * v.y;
        accv.z += cv * v.z; accv.w += cv * v.w;
      }
    }
    accv.x *= scale; accv.y *= scale; accv.z *= scale; accv.w *= scale;
    *(float4*)(pooled + (size_t)bv * HD + tid * 4) = accv;
  }
}

// ---------------- K4: out = pooled @ wc + bc ------------------------------
__global__ __launch_bounds__(256) void k_out(const float* __restrict__ pooled,
                                             const float* __restrict__ wc,
                                             const float* __restrict__ bc,
                                             float* __restrict__ out) {
  const int b0 = blockIdx.x * TB;
  const int tid = threadIdx.x;
  __shared__ float pl[TB][HD];
  for (int i = tid; i < TB * HD; i += 256) pl[i / HD][i % HD] = pooled[(size_t)b0 * HD + i];
  __syncthreads();
  float a0[TB], a1[TB];
#pragma unroll
  for (int r = 0; r < TB; ++r) { a0[r] = 0.f; a1[r] = 0.f; }
  for (int h = 0; h < HD; ++h) {
    const float w0  = wc[(size_t)h * OUTD + tid];
    const float w1v = wc[(size_t)h * OUTD + tid + 256];
#pragma unroll
    for (int r = 0; r < TB; ++r) { const float p = pl[r][h]; a0[r] += p * w0; a1[r] += p * w1v; }
  }
  const float bc0 = bc[tid], bc1 = bc[tid + 256];
#pragma unroll
  for (int r = 0; r < TB; ++r) {
    out[(size_t)(b0 + r) * OUTD + tid]       = a0[r] + bc0;
    out[(size_t)(b0 + r) * OUTD + tid + 256] = a1[r] + bc1;
  }
}

extern "C" void kernel_launch(void* const* d_in, const int* in_sizes, int n_in,
                              void* d_out, int out_size, void* d_ws, size_t ws_size,
                              hipStream_t stream) {
  const float* E     = (const float*)d_in[0];
  const float* w1    = (const float*)d_in[1];
  const float* b1    = (const float*)d_in[2];
  const float* w2    = (const float*)d_in[3];
  const float* b2    = (const float*)d_in[4];
  const float* wc    = (const float*)d_in[5];
  const float* bc    = (const float*)d_in[6];
  const float* masks = (const float*)d_in[7];
  const float* cm    = (const float*)d_in[8];
  const int*   leaves = (const int*)d_in[9];
  const int*   anc    = (const int*)d_in[10];
  const int*   ids    = (const int*)d_in[11];
  float* out = (float*)d_out;

  if (n_in < 12) return;
  if (in_sizes[0] != NTREE * HD) return;
  if (out_size != NBV * OUTD) return;

  char* ws = (char*)d_ws;
  const size_t szEbf = (size_t)NTREE * HD * 2;
  const size_t szBt  = (size_t)GNN * HD * 2;
  const size_t szPQ  = (size_t)NTREE * GNN * 2;
  const size_t szDag = (size_t)NCODES * HD * 4;
  const size_t szPl  = (size_t)NBV * HD * 4;
  if (ws_size < szEbf + szBt + szPQ + szDag + szPl) return;  // ~209 MB

  u16*   Ebf    = (u16*)ws;            ws += szEbf;
  u16*   Bt     = (u16*)ws;            ws += szBt;
  u16*   PQ     = (u16*)ws;            ws += szPQ;
  float* dag    = (float*)ws;          ws += szDag;
  float* pooled = (float*)ws;          ws += szPl;

  const int n4 = NTREE * HD / 4;
  k_convE<<<(n4 + 255) / 256, 256, 0, stream>>>(E, Ebf, n4);
  k_bt<<<(GNN * HD + 255) / 256, 256, 0, stream>>>(w1, Bt);
  k_gemm<<<GRID, 512, 0, stream>>>(Ebf, Bt, PQ);
  k_attn<<<NCODES, 512, 0, stream>>>(PQ, Ebf, b1, w2, b2, masks, leaves, anc, dag);
  k_pool<<<NBV, 256, 0, stream>>>(dag, ids, cm, pooled);
  k_out<<<NBV / TB, 256, 0, stream>>>(pooled, wc, bc, out);
}